// Round 11
// baseline (285.972 us; speedup 1.0000x reference)
//
#include <hip/hip_runtime.h>
#include <hip/hip_fp8.h>

// ---------------------------------------------------------------------------
// GraphSAGE 2-layer encoder, MI355X.
//   out = leaky( mean_{j->i}(h_j) @ Wl + b + h_i @ Wr ), slope 0.5, x2 layers
// R11: (a) GEMM counted-vmcnt now accounts for epilogue stores (vmcnt counts
// stores on CDNA!): steady-state vmcnt(S+2) leaves prev-tile stores in
// flight; store count made exact by clamping OOB rows to M-1 (value-correct:
// staging clamps identically). Grid 512 -> 2 blocks/CU. (b) agg gathers 2
// rows/instruction (half-wave per row, 8B/lane, shfl_down(32) combine),
// 16 rows in flight. (c) scan2+scan3+initcur fused; cast_x+buildB fused.
// ---------------------------------------------------------------------------

typedef __attribute__((ext_vector_type(8))) short bf16x8;
typedef __attribute__((ext_vector_type(4))) float f32x4;

__device__ __forceinline__ float bf2f(unsigned short b) {
    union { unsigned u; float f; } x; x.u = ((unsigned)b) << 16; return x.f;
}
__device__ __forceinline__ short f2bf(float f) {
    union { float f; unsigned u; } x; x.f = f;
    unsigned r = x.u + 0x7fffu + ((x.u >> 16) & 1u);
    return (short)(r >> 16);
}
__device__ __forceinline__ unsigned char f2fp8(float f) {
    __hip_fp8_e4m3 q(f);
    return (unsigned char)q.__x;
}
__device__ __forceinline__ float fp82f(unsigned char b) {
    __hip_fp8_e4m3 q; q.__x = (__hip_fp8_storage_t)b;
    return (float)q;
}

// -------------------- CSR construction --------------------

__global__ __launch_bounds__(256) void zero_kernel(int* __restrict__ p, int n4) {
    int i = blockIdx.x * 256 + threadIdx.x;
    if (i < n4) *reinterpret_cast<int4*>(p + i * 4) = (int4){0, 0, 0, 0};
}

__global__ __launch_bounds__(256) void count_kernel(
    const int* __restrict__ ei, int* __restrict__ cnt, int E) {
    int e = blockIdx.x * 256 + threadIdx.x;
    if (e < E) atomicAdd(&cnt[ei[E + e]], 1);
}

// scan1: per-block (1024) local exclusive scan of cnt -> offs, block sums.
__global__ __launch_bounds__(1024) void scan1_kernel(
    const int* __restrict__ cnt, int* __restrict__ offs,
    float* __restrict__ invdeg, int* __restrict__ bsum, int N) {
    __shared__ int wsum[16];
    int lane = threadIdx.x & 63;
    int wid = threadIdx.x >> 6;
    int i = blockIdx.x * 1024 + threadIdx.x;
    int v = (i < N) ? cnt[i] : 0;
    int s = v;
    #pragma unroll
    for (int d = 1; d < 64; d <<= 1) {
        int t = __shfl_up(s, d, 64);
        if (lane >= d) s += t;
    }
    if (lane == 63) wsum[wid] = s;
    __syncthreads();
    if (wid == 0) {
        int w = (lane < 16) ? wsum[lane] : 0;
        int ws = w;
        #pragma unroll
        for (int d = 1; d < 16; d <<= 1) {
            int t = __shfl_up(ws, d, 64);
            if (lane >= d) ws += t;
        }
        if (lane < 16) wsum[lane] = ws - w;          // exclusive wave prefix
    }
    __syncthreads();
    if (i < N) {
        offs[i] = wsum[wid] + s - v;                 // block-local exclusive
        invdeg[i] = 1.0f / (float)(v > 0 ? v : 1);
    }
    if (threadIdx.x == 1023) bsum[blockIdx.x] = wsum[15] + s;
}

// scan23: every block scans the <=64 block sums locally, adds its exclusive
// prefix to its offs range, writes offs[N], and fills bcur for its 8 buckets
// (bucket = 128 nodes; 1024-chunk = 8 buckets, aligned).
__global__ __launch_bounds__(1024) void scan23_kernel(
    int* __restrict__ offs, const int* __restrict__ bsum,
    int* __restrict__ bcur, int N, int NB, int NBK) {
    __shared__ int sh_pre, sh_tot;
    int tid = threadIdx.x;
    if (tid < 64) {
        int v = (tid < NB) ? bsum[tid] : 0;
        int s = v;
        #pragma unroll
        for (int d = 1; d < 64; d <<= 1) {
            int t = __shfl_up(s, d, 64);
            if (tid >= d) s += t;
        }
        if (tid == (int)blockIdx.x) sh_pre = s - v;
        if (tid == NB - 1) sh_tot = s;
    }
    __syncthreads();
    int i = blockIdx.x * 1024 + tid;
    int bp = sh_pre;
    if (i < N) {
        int newv = offs[i] + bp;
        offs[i] = newv;
        if ((tid & 127) == 0) {
            int b = i >> 7;
            if (b < NBK) bcur[b] = newv;
        }
    }
    if (blockIdx.x == 0 && tid == 0) offs[N] = sh_tot;
}

// binA (counting sort per block): chunk = 8192 edges; LDS histogram,
// one global atomic per (block,bucket), LDS cursors hold global positions.
#define BINA_CHUNK 8192
__global__ __launch_bounds__(512) void binA_kernel(
    const int* __restrict__ ei, int* __restrict__ bcur,
    long long* __restrict__ pairs, int E, int NBK) {
    __shared__ int hist[512];
    int base_e = blockIdx.x * BINA_CHUNK;
    int nloc = E - base_e;
    if (nloc > BINA_CHUNK) nloc = BINA_CHUNK;
    for (int b = threadIdx.x; b < NBK; b += 512) hist[b] = 0;
    __syncthreads();
    for (int t = threadIdx.x; t < nloc; t += 512)
        atomicAdd(&hist[ei[E + base_e + t] >> 7], 1);
    __syncthreads();
    for (int b = threadIdx.x; b < NBK; b += 512) {
        int h = hist[b];
        hist[b] = (h > 0) ? atomicAdd(&bcur[b], h) : 0;
    }
    __syncthreads();
    for (int t = threadIdx.x; t < nloc; t += 512) {
        int dst = ei[E + base_e + t];
        int src = ei[base_e + t];
        int pos = atomicAdd(&hist[dst >> 7], 1);
        pairs[pos] = ((long long)dst << 32) | (unsigned)src;
    }
}

// binB: one block per bucket; LDS cursors; csr writes land in 8KB window.
__global__ __launch_bounds__(256) void binB_kernel(
    const long long* __restrict__ pairs, const int* __restrict__ offs,
    int* __restrict__ csr, int NBK, int N, int E) {
    __shared__ int cur[128];
    int b = blockIdx.x;
    int t = threadIdx.x;
    if (t < 128) {
        int n0 = (b << 7) + t;
        cur[t] = (n0 < N) ? offs[n0] : 0;
    }
    __syncthreads();
    int beg = offs[b << 7];
    int eidx = (b + 1) << 7;
    if (eidx > N) eidx = N;
    int end = offs[eidx];
    for (int i = beg + t; i < end; i += 256) {
        long long p = pairs[i];
        int dst = (int)(p >> 32);
        int src = (int)(p & 0xffffffffLL);
        int pos = atomicAdd(&cur[dst & 127], 1);
        csr[pos] = src;
    }
}

// -------------------- prep: cast x (bf16/fp8/copy) + build B^T --------------------

__global__ __launch_bounds__(256) void prep_kernel(
    const float* __restrict__ x, short* __restrict__ xb,
    unsigned char* __restrict__ xq, float* __restrict__ xcopy,
    const float* __restrict__ Wl0, const float* __restrict__ Wr0,
    const float* __restrict__ Wl1, const float* __restrict__ Wr1,
    short* __restrict__ B1T, short* __restrict__ B2T, int total8) {
    int gid = blockIdx.x * 256 + threadIdx.x;
    if (gid < total8) {
        const float* p = x + (size_t)gid * 8;
        float4 v0 = *reinterpret_cast<const float4*>(p);
        float4 v1 = *reinterpret_cast<const float4*>(p + 4);
        bf16x8 t;
        t[0] = f2bf(v0.x); t[1] = f2bf(v0.y); t[2] = f2bf(v0.z); t[3] = f2bf(v0.w);
        t[4] = f2bf(v1.x); t[5] = f2bf(v1.y); t[6] = f2bf(v1.z); t[7] = f2bf(v1.w);
        *reinterpret_cast<bf16x8*>(xb + (size_t)gid * 8) = t;
        uchar4 q0, q1;
        q0.x = f2fp8(v0.x); q0.y = f2fp8(v0.y); q0.z = f2fp8(v0.z); q0.w = f2fp8(v0.w);
        q1.x = f2fp8(v1.x); q1.y = f2fp8(v1.y); q1.z = f2fp8(v1.z); q1.w = f2fp8(v1.w);
        *reinterpret_cast<uchar4*>(xq + (size_t)gid * 8) = q0;
        *reinterpret_cast<uchar4*>(xq + (size_t)gid * 8 + 4) = q1;
        *reinterpret_cast<float4*>(xcopy + (size_t)gid * 8) = v0;
        *reinterpret_cast<float4*>(xcopy + (size_t)gid * 8 + 4) = v1;
    } else {
        int idx = gid - total8;            // 0 .. 262143
        if (idx < 262144) {
            int sel = idx >> 17;
            int j = idx & 131071;
            int n = j >> 9;
            int k = j & 511;
            const float* Wl = sel ? Wl1 : Wl0;
            const float* Wr = sel ? Wr1 : Wr0;
            float v = (k < 256) ? Wl[k * 256 + n] : Wr[(k - 256) * 256 + n];
            (sel ? B2T : B1T)[j] = f2bf(v);
        }
    }
}

// -------------------- mean aggregation (fp8 gather, 2 rows/instr) ----------
// One wave per node. Half-wave per row: lane = 32*half + l32; lane loads 8B
// (8 fp8 features [l32*8, l32*8+8)) of row (pair + half). 16 rows in flight.
// Halves combined with one shfl_down(32); lanes 0-31 store 16B bf16.
__global__ __launch_bounds__(256) void agg_kernel(
    const unsigned char* __restrict__ feat,
    const int* __restrict__ offs, const int* __restrict__ csr,
    const float* __restrict__ invdeg,
    short* __restrict__ outp, int N) {
    int wave = threadIdx.x >> 6;
    int lane = threadIdx.x & 63;
    int node = blockIdx.x * 4 + wave;
    if (node >= N) return;
    int beg = offs[node];
    int end = offs[node + 1];
    int half = lane >> 5;
    int l32 = lane & 31;
    int cb = l32 * 8;

    float a[8];
    #pragma unroll
    for (int k = 0; k < 8; ++k) a[k] = 0.f;

    int deg = end - beg;
    int n16 = deg & ~15;
    for (int t = 0; t < n16; t += 16) {
        uint2 v[8];
        #pragma unroll
        for (int j = 0; j < 8; ++j) {
            int s = csr[beg + t + 2 * j + half];
            v[j] = *reinterpret_cast<const uint2*>(feat + (size_t)s * 256 + cb);
        }
        #pragma unroll
        for (int j = 0; j < 8; ++j) {
            #pragma unroll
            for (int k = 0; k < 4; ++k) a[k]     += fp82f((v[j].x >> (8 * k)) & 0xff);
            #pragma unroll
            for (int k = 0; k < 4; ++k) a[4 + k] += fp82f((v[j].y >> (8 * k)) & 0xff);
        }
    }
    int rem = beg + n16;
    int left = end - rem;
    int n2 = left & ~1;
    for (int t = 0; t < n2; t += 2) {
        int s = csr[rem + t + half];
        uint2 vv = *reinterpret_cast<const uint2*>(feat + (size_t)s * 256 + cb);
        #pragma unroll
        for (int k = 0; k < 4; ++k) a[k]     += fp82f((vv.x >> (8 * k)) & 0xff);
        #pragma unroll
        for (int k = 0; k < 4; ++k) a[4 + k] += fp82f((vv.y >> (8 * k)) & 0xff);
    }
    if (left & 1) {
        if (half == 0) {
            int s = csr[end - 1];
            uint2 vv = *reinterpret_cast<const uint2*>(feat + (size_t)s * 256 + cb);
            #pragma unroll
            for (int k = 0; k < 4; ++k) a[k]     += fp82f((vv.x >> (8 * k)) & 0xff);
            #pragma unroll
            for (int k = 0; k < 4; ++k) a[4 + k] += fp82f((vv.y >> (8 * k)) & 0xff);
        }
    }
    #pragma unroll
    for (int k = 0; k < 8; ++k) a[k] += __shfl_down(a[k], 32, 64);

    if (half == 0) {
        float inv = invdeg[node];
        bf16x8 o;
        #pragma unroll
        for (int k = 0; k < 8; ++k) o[k] = f2bf(a[k] * inv);
        *reinterpret_cast<bf16x8*>(&outp[(size_t)node * 256 + cb]) = o;
    }
}

// -------------------- fused GEMM + bias + leaky --------------------
// C[M][256] = leaky( [AL | AR][M][512](bf16) @ B[512][256] + bias )
// Persistent grid of 512 blocks (2/CU), 1024 thr = 16 waves; wave w owns
// cols [w*16, w*16+16) -- all 256 cols per block, A fetched once overall.
// breg[16] = wave's B col-slice (K=512). Tiles of 32 rows, LDS dbuf 2x32KB.
// vmcnt discipline (stores count in vmcnt on CDNA!): queue at the wait is
// [loads(cur)=2 | stores(prev)=S | loads(next)=2], S=16 (mode 0) / 8 (mode 1)
// -- exact because OOB store rows are CLAMPED to M-1 (value-correct: staging
// clamps identically, so the acc equals row M-1's result).
//   iter 0:        vmcnt(2) / vmcnt(0)      (no stores yet)
//   steady:        vmcnt(S+2)               (prev stores stay in flight)
//   last iter:     vmcnt(S)
// XOR-swizzle (r&15) via pre-swizzled GLOBAL source, linear LDS dest.
// C/D: lane l, reg r -> row (l>>4)*4+r, col l&15.
template <int OUT_MODE>   // 0: bf16 + fp8 out, 1: f32 out
__global__ __launch_bounds__(1024, 4) void gemm_kernel(
    const short* __restrict__ AL, const short* __restrict__ AR,
    const short* __restrict__ BT, const float* __restrict__ bias,
    void* __restrict__ Cout, unsigned char* __restrict__ Cq,
    int M, int ntiles) {
    __shared__ short ldsA[2][32 * 512];
    int wave = threadIdx.x >> 6;        // 0..15
    int lane = threadIdx.x & 63;
    int l16 = lane & 15;
    int lhi = lane >> 4;
    int c0 = wave * 16;

    bf16x8 breg[16];
    #pragma unroll
    for (int kk = 0; kk < 16; ++kk)
        breg[kk] = *reinterpret_cast<const bf16x8*>(
            &BT[(size_t)(c0 + l16) * 512 + kk * 32 + lhi * 8]);
    float bc = bias[c0 + l16];

    auto STAGE = [&](int tt, int buf) {
        #pragma unroll
        for (int i = 0; i < 2; ++i) {
            int r = i * 16 + wave;
            int grow = tt * 32 + r;
            if (grow >= M) grow = M - 1;
            int csw = (lane * 8) ^ ((r & 15) << 3);
            const short* src = (csw < 256)
                ? AL + (size_t)grow * 256 + csw
                : AR + (size_t)grow * 256 + (csw - 256);
            __builtin_amdgcn_global_load_lds(
                (const __attribute__((address_space(1))) unsigned int*)src,
                (__attribute__((address_space(3))) unsigned int*)
                    &ldsA[buf][r * 512],
                16, 0, 0);
        }
    };

    int t = blockIdx.x;
    int stride = gridDim.x;
    if (t >= ntiles) return;
    STAGE(t, 0);
    int buf = 0;
    int it = 0;
    for (; t < ntiles; t += stride, ++it) {
        int tn = t + stride;
        bool havenext = (tn < ntiles);
        if (havenext) STAGE(tn, buf ^ 1);

        if (it == 0) {
            if (havenext) asm volatile("s_waitcnt vmcnt(2)" ::: "memory");
            else          asm volatile("s_waitcnt vmcnt(0)" ::: "memory");
        } else if (havenext) {
            if constexpr (OUT_MODE == 0)
                asm volatile("s_waitcnt vmcnt(18)" ::: "memory");
            else
                asm volatile("s_waitcnt vmcnt(10)" ::: "memory");
        } else {
            if constexpr (OUT_MODE == 0)
                asm volatile("s_waitcnt vmcnt(16)" ::: "memory");
            else
                asm volatile("s_waitcnt vmcnt(8)" ::: "memory");
        }
        __builtin_amdgcn_s_barrier();
        __builtin_amdgcn_sched_barrier(0);

        int row0 = t * 32;
        f32x4 acc[2];
        acc[0] = (f32x4){0.f, 0.f, 0.f, 0.f};
        acc[1] = (f32x4){0.f, 0.f, 0.f, 0.f};

        const short* lb = &ldsA[buf][0];
        #pragma unroll
        for (int kk = 0; kk < 16; ++kk) {
            bf16x8 a0, a1;
            {
                int r = l16;
                int ks = (kk * 32 + lhi * 8) ^ ((r & 15) << 3);
                a0 = *reinterpret_cast<const bf16x8*>(&lb[r * 512 + ks]);
            }
            {
                int r = 16 + l16;
                int ks = (kk * 32 + lhi * 8) ^ ((r & 15) << 3);
                a1 = *reinterpret_cast<const bf16x8*>(&lb[r * 512 + ks]);
            }
            acc[0] = __builtin_amdgcn_mfma_f32_16x16x32_bf16(
                a0, breg[kk], acc[0], 0, 0, 0);
            acc[1] = __builtin_amdgcn_mfma_f32_16x16x32_bf16(
                a1, breg[kk], acc[1], 0, 0, 0);
        }

        #pragma unroll
        for (int mt = 0; mt < 2; ++mt) {
            #pragma unroll
            for (int r = 0; r < 4; ++r) {
                int grow = row0 + mt * 16 + lhi * 4 + r;
                if (grow >= M) grow = M - 1;   // clamp: value-correct, keeps
                int gcol = c0 + l16;           // store count exact for vmcnt
                float v = acc[mt][r] + bc;
                v = (v >= 0.f) ? v : 0.5f * v;
                if (OUT_MODE == 0) {
                    ((short*)Cout)[(size_t)grow * 256 + gcol] = f2bf(v);
                    Cq[(size_t)grow * 256 + gcol] = f2fp8(v);
                } else {
                    ((float*)Cout)[(size_t)grow * 256 + gcol] = v;
                }
            }
        }
        __builtin_amdgcn_s_barrier();
        buf ^= 1;
    }
}

// -------------------- launch --------------------

extern "C" void kernel_launch(void* const* d_in, const int* in_sizes, int n_in,
                              void* d_out, int out_size, void* d_ws, size_t ws_size,
                              hipStream_t stream) {
    const float* x   = (const float*)d_in[0];
    const int*   ei  = (const int*)d_in[1];   // int64 in ref -> int32 from harness
    const float* Wl0 = (const float*)d_in[2];
    const float* bl0 = (const float*)d_in[3];
    const float* Wr0 = (const float*)d_in[4];
    const float* Wl1 = (const float*)d_in[5];
    const float* bl1 = (const float*)d_in[6];
    const float* Wr1 = (const float*)d_in[7];

    const int N = in_sizes[0] / 256;
    const int E = in_sizes[1] / 2;
    const int NBK = (N + 127) / 128;           // <= 512

    char* ws = (char*)d_ws;
    size_t o = 0;
    auto alloc = [&](size_t bytes) {
        size_t p = o;
        o = (o + bytes + 255) & ~(size_t)255;
        return p;
    };
    int*   cnt    = (int*)  (ws + alloc((size_t)N * 4));
    int*   offs   = (int*)  (ws + alloc((size_t)(N + 1) * 4));
    float* invdeg = (float*)(ws + alloc((size_t)N * 4));
    int*   bsum   = (int*)  (ws + alloc(64 * 4));
    int*   bcur   = (int*)  (ws + alloc((size_t)NBK * 4));
    long long* pairs = (long long*)(ws + alloc((size_t)E * 8));
    int*   csr    = (int*)  (ws + alloc((size_t)E * 4));
    short* xb     = (short*)(ws + alloc((size_t)N * 256 * 2));
    short* meanb  = (short*)(ws + alloc((size_t)N * 256 * 2));   // reused L0/L1
    short* h0     = (short*)(ws + alloc((size_t)N * 256 * 2));
    unsigned char* xq  = (unsigned char*)(ws + alloc((size_t)N * 256));
    unsigned char* h0q = (unsigned char*)(ws + alloc((size_t)N * 256));
    short* B1T    = (short*)(ws + alloc(262144));
    short* B2T    = (short*)(ws + alloc(262144));

    int eb = (E + 255) / 256;
    int NB = (N + 1023) / 1024;
    zero_kernel<<<((N + 3) / 4 + 255) / 256, 256, 0, stream>>>(cnt, (N + 3) / 4);
    count_kernel<<<eb, 256, 0, stream>>>(ei, cnt, E);
    scan1_kernel<<<NB, 1024, 0, stream>>>(cnt, offs, invdeg, bsum, N);
    scan23_kernel<<<NB, 1024, 0, stream>>>(offs, bsum, bcur, N, NB, NBK);
    binA_kernel<<<(E + BINA_CHUNK - 1) / BINA_CHUNK, 512, 0, stream>>>(
        ei, bcur, pairs, E, NBK);
    binB_kernel<<<NBK, 256, 0, stream>>>(pairs, offs, csr, NBK, N, E);

    int total8 = N * 32;
    int prep_threads = total8 + 262144;
    prep_kernel<<<(prep_threads + 255) / 256, 256, 0, stream>>>(
        x, xb, xq, (float*)d_out + (size_t)N * 256,
        Wl0, Wr0, Wl1, Wr1, B1T, B2T, total8);

    int ab = (N + 3) / 4;
    int ntiles = (N + 31) / 32;
    int gblocks = 512;
    // layer 0
    agg_kernel<<<ab, 256, 0, stream>>>(xq, offs, csr, invdeg, meanb, N);
    gemm_kernel<0><<<gblocks, 1024, 0, stream>>>(
        meanb, xb, B1T, bl0, h0, h0q, N, ntiles);
    // layer 1
    agg_kernel<<<ab, 256, 0, stream>>>(h0q, offs, csr, invdeg, meanb, N);
    gemm_kernel<1><<<gblocks, 1024, 0, stream>>>(
        meanb, h0, B2T, bl1, d_out, nullptr, N, ntiles);
}

// Round 12
// 239.419 us; speedup vs baseline: 1.1944x; 1.1944x over previous
//
#include <hip/hip_runtime.h>
#include <hip/hip_fp8.h>

// ---------------------------------------------------------------------------
// GraphSAGE 2-layer encoder, MI355X.
//   out = leaky( mean_{j->i}(h_j) @ Wl + b + h_i @ Wr ), slope 0.5, x2 layers
// R12: (a) REVERT agg to R10's 8-row-in-flight 4B/lane gather (R11's paired
// scheme broke MLP for deg<16 nodes: 59us vs 30us). (b) CSR chain rebuilt at
// bucket granularity: bkcount (LDS hist, ~40K global atomics) -> bkscan
// (1 block over 391 buckets) -> binA (unchanged) -> binB (derives per-node
// offs+invdeg from its L2-hot pair window via LDS hist + 64-lane scan).
// Removes count/scan1/scan23 (three N-sized passes, 800K global atomics).
// GEMM unchanged from R11 (persistent 16-wave, dbuf, store-exact vmcnt).
// ---------------------------------------------------------------------------

typedef __attribute__((ext_vector_type(8))) short bf16x8;
typedef __attribute__((ext_vector_type(4))) float f32x4;

__device__ __forceinline__ float bf2f(unsigned short b) {
    union { unsigned u; float f; } x; x.u = ((unsigned)b) << 16; return x.f;
}
__device__ __forceinline__ short f2bf(float f) {
    union { float f; unsigned u; } x; x.f = f;
    unsigned r = x.u + 0x7fffu + ((x.u >> 16) & 1u);
    return (short)(r >> 16);
}
__device__ __forceinline__ unsigned char f2fp8(float f) {
    __hip_fp8_e4m3 q(f);
    return (unsigned char)q.__x;
}
__device__ __forceinline__ float fp82f(unsigned char b) {
    __hip_fp8_e4m3 q; q.__x = (__hip_fp8_storage_t)b;
    return (float)q;
}

// -------------------- CSR construction (bucket-granular) --------------------

__global__ __launch_bounds__(256) void zero_kernel(int* __restrict__ p, int n4) {
    int i = blockIdx.x * 256 + threadIdx.x;
    if (i < n4) *reinterpret_cast<int4*>(p + i * 4) = (int4){0, 0, 0, 0};
}

// bucket counts: LDS histogram per 8192-edge chunk, one global atomic per
// (block, non-empty bucket).
#define BINA_CHUNK 8192
__global__ __launch_bounds__(512) void bkcount_kernel(
    const int* __restrict__ ei, int* __restrict__ bkcnt, int E, int NBK) {
    __shared__ int hist[512];
    int base_e = blockIdx.x * BINA_CHUNK;
    int nloc = E - base_e;
    if (nloc > BINA_CHUNK) nloc = BINA_CHUNK;
    for (int b = threadIdx.x; b < NBK; b += 512) hist[b] = 0;
    __syncthreads();
    for (int t = threadIdx.x; t < nloc; t += 512)
        atomicAdd(&hist[ei[E + base_e + t] >> 7], 1);
    __syncthreads();
    for (int b = threadIdx.x; b < NBK; b += 512) {
        int h = hist[b];
        if (h > 0) atomicAdd(&bkcnt[b], h);
    }
}

// one block: exclusive-scan bucket counts -> bkoff, init bcur, offs[N]=E.
__global__ __launch_bounds__(512) void bkscan_kernel(
    const int* __restrict__ bkcnt, int* __restrict__ bkoff,
    int* __restrict__ bcur, int* __restrict__ offs, int NBK, int N, int E) {
    __shared__ int sm[512];
    int tid = threadIdx.x;
    int v = (tid < NBK) ? bkcnt[tid] : 0;
    sm[tid] = v;
    __syncthreads();
    for (int off = 1; off < 512; off <<= 1) {
        int t = (tid >= off) ? sm[tid - off] : 0;
        __syncthreads();
        sm[tid] += t;
        __syncthreads();
    }
    if (tid < NBK) {
        int e = sm[tid] - v;
        bkoff[tid] = e;
        bcur[tid] = e;
    }
    if (tid == 0) {
        bkoff[NBK] = E;
        offs[N] = E;
    }
}

// binA (counting sort per block): chunk = 8192 edges; LDS histogram,
// one global atomic per (block,bucket), LDS cursors hold global positions.
__global__ __launch_bounds__(512) void binA_kernel(
    const int* __restrict__ ei, int* __restrict__ bcur,
    long long* __restrict__ pairs, int E, int NBK) {
    __shared__ int hist[512];
    int base_e = blockIdx.x * BINA_CHUNK;
    int nloc = E - base_e;
    if (nloc > BINA_CHUNK) nloc = BINA_CHUNK;
    for (int b = threadIdx.x; b < NBK; b += 512) hist[b] = 0;
    __syncthreads();
    for (int t = threadIdx.x; t < nloc; t += 512)
        atomicAdd(&hist[ei[E + base_e + t] >> 7], 1);
    __syncthreads();
    for (int b = threadIdx.x; b < NBK; b += 512) {
        int h = hist[b];
        hist[b] = (h > 0) ? atomicAdd(&bcur[b], h) : 0;
    }
    __syncthreads();
    for (int t = threadIdx.x; t < nloc; t += 512) {
        int dst = ei[E + base_e + t];
        int src = ei[base_e + t];
        int pos = atomicAdd(&hist[dst >> 7], 1);
        pairs[pos] = ((long long)dst << 32) | (unsigned)src;
    }
}

// binB: one block per bucket. Derives per-node offsets from its (L2-hot)
// pair window: LDS hist over 128 nodes -> 64-lane scan -> offs/invdeg ->
// LDS-cursor scatter into the bucket's csr window.
__global__ __launch_bounds__(256) void binB_kernel(
    const long long* __restrict__ pairs, const int* __restrict__ bkoff,
    int* __restrict__ offs, float* __restrict__ invdeg,
    int* __restrict__ csr, int NBK, int N) {
    __shared__ int cnt[128];
    __shared__ int cur[128];
    int b = blockIdx.x;
    int t = threadIdx.x;
    if (t < 128) cnt[t] = 0;
    __syncthreads();
    int beg = bkoff[b];
    int end = bkoff[b + 1];
    for (int i = beg + t; i < end; i += 256)
        atomicAdd(&cnt[((int)(pairs[i] >> 32)) & 127], 1);
    __syncthreads();
    if (t < 64) {
        int c0 = cnt[2 * t], c1 = cnt[2 * t + 1];
        int s = c0 + c1;
        int incl = s;
        #pragma unroll
        for (int d = 1; d < 64; d <<= 1) {
            int x = __shfl_up(incl, d, 64);
            if (t >= d) incl += x;
        }
        int excl = incl - s;
        cur[2 * t] = beg + excl;
        cur[2 * t + 1] = beg + excl + c0;
    }
    __syncthreads();
    if (t < 128) {
        int node = (b << 7) + t;
        if (node < N) {
            offs[node] = cur[t];
            invdeg[node] = 1.0f / (float)(cnt[t] > 0 ? cnt[t] : 1);
        }
    }
    __syncthreads();
    for (int i = beg + t; i < end; i += 256) {
        long long p = pairs[i];
        int pos = atomicAdd(&cur[((int)(p >> 32)) & 127], 1);
        csr[pos] = (int)(p & 0xffffffffLL);
    }
}

// -------------------- prep: cast x (bf16/fp8/copy) + build B^T --------------------

__global__ __launch_bounds__(256) void prep_kernel(
    const float* __restrict__ x, short* __restrict__ xb,
    unsigned char* __restrict__ xq, float* __restrict__ xcopy,
    const float* __restrict__ Wl0, const float* __restrict__ Wr0,
    const float* __restrict__ Wl1, const float* __restrict__ Wr1,
    short* __restrict__ B1T, short* __restrict__ B2T, int total8) {
    int gid = blockIdx.x * 256 + threadIdx.x;
    if (gid < total8) {
        const float* p = x + (size_t)gid * 8;
        float4 v0 = *reinterpret_cast<const float4*>(p);
        float4 v1 = *reinterpret_cast<const float4*>(p + 4);
        bf16x8 t;
        t[0] = f2bf(v0.x); t[1] = f2bf(v0.y); t[2] = f2bf(v0.z); t[3] = f2bf(v0.w);
        t[4] = f2bf(v1.x); t[5] = f2bf(v1.y); t[6] = f2bf(v1.z); t[7] = f2bf(v1.w);
        *reinterpret_cast<bf16x8*>(xb + (size_t)gid * 8) = t;
        uchar4 q0, q1;
        q0.x = f2fp8(v0.x); q0.y = f2fp8(v0.y); q0.z = f2fp8(v0.z); q0.w = f2fp8(v0.w);
        q1.x = f2fp8(v1.x); q1.y = f2fp8(v1.y); q1.z = f2fp8(v1.z); q1.w = f2fp8(v1.w);
        *reinterpret_cast<uchar4*>(xq + (size_t)gid * 8) = q0;
        *reinterpret_cast<uchar4*>(xq + (size_t)gid * 8 + 4) = q1;
        *reinterpret_cast<float4*>(xcopy + (size_t)gid * 8) = v0;
        *reinterpret_cast<float4*>(xcopy + (size_t)gid * 8 + 4) = v1;
    } else {
        int idx = gid - total8;            // 0 .. 262143
        if (idx < 262144) {
            int sel = idx >> 17;
            int j = idx & 131071;
            int n = j >> 9;
            int k = j & 511;
            const float* Wl = sel ? Wl1 : Wl0;
            const float* Wr = sel ? Wr1 : Wr0;
            float v = (k < 256) ? Wl[k * 256 + n] : Wr[(k - 256) * 256 + n];
            (sel ? B2T : B1T)[j] = f2bf(v);
        }
    }
}

// -------------------- mean aggregation (fp8 gather) --------------------
// R10 version (reverted): one wave per node; lane t owns elements [4t,4t+4)
// (4B fp8/lane). 8 independent row loads in flight.
__global__ __launch_bounds__(256) void agg_kernel(
    const unsigned char* __restrict__ feat,
    const int* __restrict__ offs, const int* __restrict__ csr,
    const float* __restrict__ invdeg,
    short* __restrict__ outp, int N) {
    int wave = threadIdx.x >> 6;
    int lane = threadIdx.x & 63;
    int node = blockIdx.x * 4 + wave;
    if (node >= N) return;
    int beg = offs[node];
    int end = offs[node + 1];
    int c = lane * 4;

    float a[4][4];
    #pragma unroll
    for (int u = 0; u < 4; ++u)
        #pragma unroll
        for (int k = 0; k < 4; ++k) a[u][k] = 0.f;

    int deg = end - beg;
    int n8 = deg & ~7;
    for (int t = 0; t < n8; t += 8) {
        int s0 = csr[beg + t];     int s1 = csr[beg + t + 1];
        int s2 = csr[beg + t + 2]; int s3 = csr[beg + t + 3];
        int s4 = csr[beg + t + 4]; int s5 = csr[beg + t + 5];
        int s6 = csr[beg + t + 6]; int s7 = csr[beg + t + 7];
        unsigned u0 = *reinterpret_cast<const unsigned*>(feat + (size_t)s0 * 256 + c);
        unsigned u1 = *reinterpret_cast<const unsigned*>(feat + (size_t)s1 * 256 + c);
        unsigned u2 = *reinterpret_cast<const unsigned*>(feat + (size_t)s2 * 256 + c);
        unsigned u3 = *reinterpret_cast<const unsigned*>(feat + (size_t)s3 * 256 + c);
        unsigned u4 = *reinterpret_cast<const unsigned*>(feat + (size_t)s4 * 256 + c);
        unsigned u5 = *reinterpret_cast<const unsigned*>(feat + (size_t)s5 * 256 + c);
        unsigned u6 = *reinterpret_cast<const unsigned*>(feat + (size_t)s6 * 256 + c);
        unsigned u7 = *reinterpret_cast<const unsigned*>(feat + (size_t)s7 * 256 + c);
        #pragma unroll
        for (int k = 0; k < 4; ++k) a[0][k] += fp82f((u0 >> (8 * k)) & 0xff);
        #pragma unroll
        for (int k = 0; k < 4; ++k) a[1][k] += fp82f((u1 >> (8 * k)) & 0xff);
        #pragma unroll
        for (int k = 0; k < 4; ++k) a[2][k] += fp82f((u2 >> (8 * k)) & 0xff);
        #pragma unroll
        for (int k = 0; k < 4; ++k) a[3][k] += fp82f((u3 >> (8 * k)) & 0xff);
        #pragma unroll
        for (int k = 0; k < 4; ++k) a[0][k] += fp82f((u4 >> (8 * k)) & 0xff);
        #pragma unroll
        for (int k = 0; k < 4; ++k) a[1][k] += fp82f((u5 >> (8 * k)) & 0xff);
        #pragma unroll
        for (int k = 0; k < 4; ++k) a[2][k] += fp82f((u6 >> (8 * k)) & 0xff);
        #pragma unroll
        for (int k = 0; k < 4; ++k) a[3][k] += fp82f((u7 >> (8 * k)) & 0xff);
    }
    for (int e = beg + n8; e < end; ++e) {
        int s = csr[e];
        unsigned u = *reinterpret_cast<const unsigned*>(feat + (size_t)s * 256 + c);
        #pragma unroll
        for (int k = 0; k < 4; ++k) a[0][k] += fp82f((u >> (8 * k)) & 0xff);
    }
    float inv = invdeg[node];
    short4 o;
    o.x = f2bf((a[0][0] + a[1][0] + a[2][0] + a[3][0]) * inv);
    o.y = f2bf((a[0][1] + a[1][1] + a[2][1] + a[3][1]) * inv);
    o.z = f2bf((a[0][2] + a[1][2] + a[2][2] + a[3][2]) * inv);
    o.w = f2bf((a[0][3] + a[1][3] + a[2][3] + a[3][3]) * inv);
    *reinterpret_cast<short4*>(&outp[(size_t)node * 256 + c]) = o;
}

// -------------------- fused GEMM + bias + leaky --------------------
// (unchanged from R11; see R11 comments for vmcnt store accounting)
template <int OUT_MODE>   // 0: bf16 + fp8 out, 1: f32 out
__global__ __launch_bounds__(1024, 4) void gemm_kernel(
    const short* __restrict__ AL, const short* __restrict__ AR,
    const short* __restrict__ BT, const float* __restrict__ bias,
    void* __restrict__ Cout, unsigned char* __restrict__ Cq,
    int M, int ntiles) {
    __shared__ short ldsA[2][32 * 512];
    int wave = threadIdx.x >> 6;        // 0..15
    int lane = threadIdx.x & 63;
    int l16 = lane & 15;
    int lhi = lane >> 4;
    int c0 = wave * 16;

    bf16x8 breg[16];
    #pragma unroll
    for (int kk = 0; kk < 16; ++kk)
        breg[kk] = *reinterpret_cast<const bf16x8*>(
            &BT[(size_t)(c0 + l16) * 512 + kk * 32 + lhi * 8]);
    float bc = bias[c0 + l16];

    auto STAGE = [&](int tt, int buf) {
        #pragma unroll
        for (int i = 0; i < 2; ++i) {
            int r = i * 16 + wave;
            int grow = tt * 32 + r;
            if (grow >= M) grow = M - 1;
            int csw = (lane * 8) ^ ((r & 15) << 3);
            const short* src = (csw < 256)
                ? AL + (size_t)grow * 256 + csw
                : AR + (size_t)grow * 256 + (csw - 256);
            __builtin_amdgcn_global_load_lds(
                (const __attribute__((address_space(1))) unsigned int*)src,
                (__attribute__((address_space(3))) unsigned int*)
                    &ldsA[buf][r * 512],
                16, 0, 0);
        }
    };

    int t = blockIdx.x;
    int stride = gridDim.x;
    if (t >= ntiles) return;
    STAGE(t, 0);
    int buf = 0;
    int it = 0;
    for (; t < ntiles; t += stride, ++it) {
        int tn = t + stride;
        bool havenext = (tn < ntiles);
        if (havenext) STAGE(tn, buf ^ 1);

        if (it == 0) {
            if (havenext) asm volatile("s_waitcnt vmcnt(2)" ::: "memory");
            else          asm volatile("s_waitcnt vmcnt(0)" ::: "memory");
        } else if (havenext) {
            if constexpr (OUT_MODE == 0)
                asm volatile("s_waitcnt vmcnt(18)" ::: "memory");
            else
                asm volatile("s_waitcnt vmcnt(10)" ::: "memory");
        } else {
            if constexpr (OUT_MODE == 0)
                asm volatile("s_waitcnt vmcnt(16)" ::: "memory");
            else
                asm volatile("s_waitcnt vmcnt(8)" ::: "memory");
        }
        __builtin_amdgcn_s_barrier();
        __builtin_amdgcn_sched_barrier(0);

        int row0 = t * 32;
        f32x4 acc[2];
        acc[0] = (f32x4){0.f, 0.f, 0.f, 0.f};
        acc[1] = (f32x4){0.f, 0.f, 0.f, 0.f};

        const short* lb = &ldsA[buf][0];
        #pragma unroll
        for (int kk = 0; kk < 16; ++kk) {
            bf16x8 a0, a1;
            {
                int r = l16;
                int ks = (kk * 32 + lhi * 8) ^ ((r & 15) << 3);
                a0 = *reinterpret_cast<const bf16x8*>(&lb[r * 512 + ks]);
            }
            {
                int r = 16 + l16;
                int ks = (kk * 32 + lhi * 8) ^ ((r & 15) << 3);
                a1 = *reinterpret_cast<const bf16x8*>(&lb[r * 512 + ks]);
            }
            acc[0] = __builtin_amdgcn_mfma_f32_16x16x32_bf16(
                a0, breg[kk], acc[0], 0, 0, 0);
            acc[1] = __builtin_amdgcn_mfma_f32_16x16x32_bf16(
                a1, breg[kk], acc[1], 0, 0, 0);
        }

        #pragma unroll
        for (int mt = 0; mt < 2; ++mt) {
            #pragma unroll
            for (int r = 0; r < 4; ++r) {
                int grow = row0 + mt * 16 + lhi * 4 + r;
                if (grow >= M) grow = M - 1;   // clamp: value-correct, keeps
                int gcol = c0 + l16;           // store count exact for vmcnt
                float v = acc[mt][r] + bc;
                v = (v >= 0.f) ? v : 0.5f * v;
                if (OUT_MODE == 0) {
                    ((short*)Cout)[(size_t)grow * 256 + gcol] = f2bf(v);
                    Cq[(size_t)grow * 256 + gcol] = f2fp8(v);
                } else {
                    ((float*)Cout)[(size_t)grow * 256 + gcol] = v;
                }
            }
        }
        __builtin_amdgcn_s_barrier();
        buf ^= 1;
    }
}

// -------------------- launch --------------------

extern "C" void kernel_launch(void* const* d_in, const int* in_sizes, int n_in,
                              void* d_out, int out_size, void* d_ws, size_t ws_size,
                              hipStream_t stream) {
    const float* x   = (const float*)d_in[0];
    const int*   ei  = (const int*)d_in[1];   // int64 in ref -> int32 from harness
    const float* Wl0 = (const float*)d_in[2];
    const float* bl0 = (const float*)d_in[3];
    const float* Wr0 = (const float*)d_in[4];
    const float* Wl1 = (const float*)d_in[5];
    const float* bl1 = (const float*)d_in[6];
    const float* Wr1 = (const float*)d_in[7];

    const int N = in_sizes[0] / 256;
    const int E = in_sizes[1] / 2;
    const int NBK = (N + 127) / 128;           // <= 512

    char* ws = (char*)d_ws;
    size_t o = 0;
    auto alloc = [&](size_t bytes) {
        size_t p = o;
        o = (o + bytes + 255) & ~(size_t)255;
        return p;
    };
    int*   offs   = (int*)  (ws + alloc((size_t)(N + 1) * 4));
    float* invdeg = (float*)(ws + alloc((size_t)N * 4));
    int*   bkcnt  = (int*)  (ws + alloc(((size_t)NBK + 4) * 4));
    int*   bkoff  = (int*)  (ws + alloc(((size_t)NBK + 1) * 4));
    int*   bcur   = (int*)  (ws + alloc((size_t)NBK * 4));
    long long* pairs = (long long*)(ws + alloc((size_t)E * 8));
    int*   csr    = (int*)  (ws + alloc((size_t)E * 4));
    short* xb     = (short*)(ws + alloc((size_t)N * 256 * 2));
    short* meanb  = (short*)(ws + alloc((size_t)N * 256 * 2));   // reused L0/L1
    short* h0     = (short*)(ws + alloc((size_t)N * 256 * 2));
    unsigned char* xq  = (unsigned char*)(ws + alloc((size_t)N * 256));
    unsigned char* h0q = (unsigned char*)(ws + alloc((size_t)N * 256));
    short* B1T    = (short*)(ws + alloc(262144));
    short* B2T    = (short*)(ws + alloc(262144));

    int ebk = (E + BINA_CHUNK - 1) / BINA_CHUNK;
    zero_kernel<<<1, 256, 0, stream>>>(bkcnt, (NBK + 3) / 4);
    bkcount_kernel<<<ebk, 512, 0, stream>>>(ei, bkcnt, E, NBK);
    bkscan_kernel<<<1, 512, 0, stream>>>(bkcnt, bkoff, bcur, offs, NBK, N, E);
    binA_kernel<<<ebk, 512, 0, stream>>>(ei, bcur, pairs, E, NBK);
    binB_kernel<<<NBK, 256, 0, stream>>>(pairs, bkoff, offs, invdeg, csr, NBK, N);

    int total8 = N * 32;
    int prep_threads = total8 + 262144;
    prep_kernel<<<(prep_threads + 255) / 256, 256, 0, stream>>>(
        x, xb, xq, (float*)d_out + (size_t)N * 256,
        Wl0, Wr0, Wl1, Wr1, B1T, B2T, total8);

    int ab = (N + 3) / 4;
    int ntiles = (N + 31) / 32;
    int gblocks = 512;
    // layer 0
    agg_kernel<<<ab, 256, 0, stream>>>(xq, offs, csr, invdeg, meanb, N);
    gemm_kernel<0><<<gblocks, 1024, 0, stream>>>(
        meanb, xb, B1T, bl0, h0, h0q, N, ntiles);
    // layer 1
    agg_kernel<<<ab, 256, 0, stream>>>(h0q, offs, csr, invdeg, meanb, N);
    gemm_kernel<1><<<gblocks, 1024, 0, stream>>>(
        meanb, h0, B2T, bl1, d_out, nullptr, N, ntiles);
}